// Round 1
// baseline (40370.755 us; speedup 1.0000x reference)
//
#include <hip/hip_runtime.h>
#include <cmath>

#define NB 64
#define NT 2048
#define ND 256
#define NH 256
#define SLICE 64
#define NTHR 512

__device__ __forceinline__ float sigmoid_f(float x) {
    return 1.0f / (1.0f + __expf(-x));
}
__device__ __forceinline__ float tanh_f(float x) {
    // tanh(x) = 1 - 2/(exp(2x)+1); saturates correctly for large |x|
    return 1.0f - 2.0f / (1.0f + __expf(2.0f * x));
}

// Grid: 256 WGs x 512 threads. WG -> (batch, slice-of-64-outputs).
// The 4 WGs of a batch are co-located on one XCD (bid&7 mapping) and exchange
// v = r*h_prev and h_new each step via agent-scope atomics + monotone flags.
extern "C" __global__ void __launch_bounds__(NTHR, 2)
gru_persistent(const float* __restrict__ x,
               const float* __restrict__ Wz, const float* __restrict__ bz,
               const float* __restrict__ Wr, const float* __restrict__ br,
               const float* __restrict__ Wh, const float* __restrict__ bh,
               float* __restrict__ out,
               float* hglob, float* vglob,
               unsigned* flagv, unsigned* flagh)
{
    __shared__ __align__(16) float xbuf[ND];
    __shared__ __align__(16) float hbuf[NH];
    __shared__ __align__(16) float vbuf[NH];
    __shared__ __align__(16) float pz[8][64];
    __shared__ __align__(16) float pr[8][64];
    __shared__ __align__(16) float ph[8][64];

    const int tid = threadIdx.x;
    const int j   = tid & 63;     // lane within wave
    const int p   = tid >> 6;     // wave id 0..7 == input chunk
    const int bid = blockIdx.x;
    const int xcd   = bid & 7;
    const int slot  = bid >> 3;
    const int batch = xcd * 8 + (slot >> 2);
    const int slice = slot & 3;
    const int j0    = slice * SLICE;
    const int c     = j0 + j;     // output column this thread owns

    // ---- register-resident weight slices: rows p*64..p*64+63, column c ----
    float wz[64], wr[64], wh[64];
    {
        const int rowbase = p * 64;
        #pragma unroll
        for (int k = 0; k < 64; ++k) {
            wz[k] = Wz[(rowbase + k) * NH + c];
            wr[k] = Wr[(rowbase + k) * NH + c];
            wh[k] = Wh[(rowbase + k) * NH + c];
        }
    }
    float bzv = 0.f, brv = 0.f, bhv = 0.f;
    if (p == 0) { bzv = bz[c]; bhv = bh[c]; }
    if (p == 1) { brv = br[c]; }

    // ---- init LDS state ----
    if (tid < NH) { hbuf[tid] = 0.f; vbuf[tid] = 0.f; }
    if (p == 6) {  // x[batch][0][:]
        const float4 xv = *reinterpret_cast<const float4*>(
            &x[(size_t)batch * NT * ND + (size_t)j * 4]);
        *reinterpret_cast<float4*>(&xbuf[j * 4]) = xv;
    }
    __syncthreads();

    const float* inA = (p < 4) ? &xbuf[p * 64] : &hbuf[(p - 4) * 64];
    const float* inB = (p < 4) ? &xbuf[p * 64] : &vbuf[(p - 4) * 64];

    float zreg = 0.f;  // p==0 only: z gate for this thread's output
    float hreg = 0.f;  // p==0 only: own h_prev value

    for (int t = 0; t < NT; ++t) {
        // ---------------- stage A: z,r partials over this wave's 64 inputs ----
        float az = 0.f, ar = 0.f;
        #pragma unroll
        for (int k4 = 0; k4 < 16; ++k4) {
            const float4 iv = *reinterpret_cast<const float4*>(&inA[k4 * 4]);
            az = fmaf(iv.x, wz[k4*4+0], az); ar = fmaf(iv.x, wr[k4*4+0], ar);
            az = fmaf(iv.y, wz[k4*4+1], az); ar = fmaf(iv.y, wr[k4*4+1], ar);
            az = fmaf(iv.z, wz[k4*4+2], az); ar = fmaf(iv.z, wr[k4*4+2], ar);
            az = fmaf(iv.w, wz[k4*4+3], az); ar = fmaf(iv.w, wr[k4*4+3], ar);
        }
        pz[p][j] = az;
        pr[p][j] = ar;
        __syncthreads();  // bar1

        if (p == 0) {
            float s = bzv;
            #pragma unroll
            for (int q = 0; q < 8; ++q) s += pz[q][j];
            zreg = sigmoid_f(s);
        } else if (p == 1) {
            float s = brv;
            #pragma unroll
            for (int q = 0; q < 8; ++q) s += pr[q][j];
            const float r = sigmoid_f(s);
            const float v = r * hbuf[j0 + j];
            vbuf[j0 + j] = v;
            __hip_atomic_store(&vglob[batch * NH + j0 + j], v,
                               __ATOMIC_RELAXED, __HIP_MEMORY_SCOPE_AGENT);
            asm volatile("s_waitcnt vmcnt(0)" ::: "memory");
            if (j == 0)
                __hip_atomic_store(&flagv[batch * 4 + slice], (unsigned)(t + 1),
                                   __ATOMIC_RELEASE, __HIP_MEMORY_SCOPE_AGENT);
        } else if (p == 7) {
            if (j < 3) {  // spin on the 3 peers' v flags
                const int ps = (slice + 1 + j) & 3;
                unsigned iters = 0;
                while (__hip_atomic_load(&flagv[batch * 4 + ps],
                                         __ATOMIC_ACQUIRE, __HIP_MEMORY_SCOPE_AGENT)
                       < (unsigned)(t + 1)) {
                    __builtin_amdgcn_s_sleep(1);
                    if (++iters > (1u << 20)) break;  // hang-safety bailout
                }
            }
            #pragma unroll
            for (int q = 1; q <= 3; ++q) {
                const int ps = (slice + q) & 3;
                vbuf[ps * 64 + j] = __hip_atomic_load(
                    &vglob[batch * NH + ps * 64 + j],
                    __ATOMIC_RELAXED, __HIP_MEMORY_SCOPE_AGENT);
            }
        }
        __syncthreads();  // bar2: full v vector in vbuf

        // ---------------- stage B: h_hat partials over [x | v] --------------
        float ah = 0.f;
        #pragma unroll
        for (int k4 = 0; k4 < 16; ++k4) {
            const float4 iv = *reinterpret_cast<const float4*>(&inB[k4 * 4]);
            ah = fmaf(iv.x, wh[k4*4+0], ah);
            ah = fmaf(iv.y, wh[k4*4+1], ah);
            ah = fmaf(iv.z, wh[k4*4+2], ah);
            ah = fmaf(iv.w, wh[k4*4+3], ah);
        }
        ph[p][j] = ah;
        __syncthreads();  // bar3

        if (p == 0) {
            float s = bhv;
            #pragma unroll
            for (int q = 0; q < 8; ++q) s += ph[q][j];
            const float hh = tanh_f(s);
            const float hn = (1.0f - zreg) * hreg + zreg * hh;
            hreg = hn;
            out[(size_t)batch * NT * NH + (size_t)t * NH + c] = hn;
            hbuf[j0 + j] = hn;
            __hip_atomic_store(&hglob[batch * NH + j0 + j], hn,
                               __ATOMIC_RELAXED, __HIP_MEMORY_SCOPE_AGENT);
            asm volatile("s_waitcnt vmcnt(0)" ::: "memory");
            if (j == 0)
                __hip_atomic_store(&flagh[batch * 4 + slice], (unsigned)(t + 1),
                                   __ATOMIC_RELEASE, __HIP_MEMORY_SCOPE_AGENT);
        } else if (p == 7) {
            if (j < 3) {
                const int ps = (slice + 1 + j) & 3;
                unsigned iters = 0;
                while (__hip_atomic_load(&flagh[batch * 4 + ps],
                                         __ATOMIC_ACQUIRE, __HIP_MEMORY_SCOPE_AGENT)
                       < (unsigned)(t + 1)) {
                    __builtin_amdgcn_s_sleep(1);
                    if (++iters > (1u << 20)) break;
                }
            }
            #pragma unroll
            for (int q = 1; q <= 3; ++q) {
                const int ps = (slice + q) & 3;
                hbuf[ps * 64 + j] = __hip_atomic_load(
                    &hglob[batch * NH + ps * 64 + j],
                    __ATOMIC_RELAXED, __HIP_MEMORY_SCOPE_AGENT);
            }
        } else if (p == 6) {
            if (t + 1 < NT) {  // prefetch x[batch][t+1][:] into xbuf
                const float4 xv = *reinterpret_cast<const float4*>(
                    &x[(size_t)batch * NT * ND + (size_t)(t + 1) * ND + (size_t)j * 4]);
                *reinterpret_cast<float4*>(&xbuf[j * 4]) = xv;
            }
        }
        __syncthreads();  // bar4: hbuf = h_t complete, xbuf = x_{t+1}
    }
}

extern "C" void kernel_launch(void* const* d_in, const int* in_sizes, int n_in,
                              void* d_out, int out_size, void* d_ws, size_t ws_size,
                              hipStream_t stream) {
    const float* x  = (const float*)d_in[0];
    const float* Wz = (const float*)d_in[1];
    const float* bz = (const float*)d_in[2];
    const float* Wr = (const float*)d_in[3];
    const float* br = (const float*)d_in[4];
    const float* Wh = (const float*)d_in[5];
    const float* bh = (const float*)d_in[6];
    float* outp = (float*)d_out;

    float* hglob = (float*)d_ws;                 // [NB][NH]
    float* vglob = hglob + NB * NH;              // [NB][NH]
    unsigned* flagv = (unsigned*)(vglob + NB * NH);  // [NB][4]
    unsigned* flagh = flagv + NB * 4;                // [NB][4]

    // flags must start at 0 every launch (monotone t+1 counters)
    hipMemsetAsync(flagv, 0, 2 * NB * 4 * sizeof(unsigned), stream);

    gru_persistent<<<256, NTHR, 0, stream>>>(x, Wz, bz, Wr, br, Wh, bh,
                                             outp, hglob, vglob, flagv, flagh);
}